// Round 3
// baseline (360.330 us; speedup 1.0000x reference)
//
#include <hip/hip_runtime.h>

#define N_NODES 50000
#define N_EDGES 600000
#define CH 128
#define NUM_GRAPHS 512
#define OUT_CH 64

// ---------------- CSR build (counting sort by dst) ----------------

__global__ void k_count(const int* __restrict__ dst, int* __restrict__ deg) {
    int e = blockIdx.x * 256 + threadIdx.x;
    if (e < N_EDGES) atomicAdd(&deg[dst[e]], 1);
}

__global__ void k_scan1(const int* __restrict__ deg, int* __restrict__ off,
                        int* __restrict__ bsum) {
    __shared__ int sd[256];
    int tid = threadIdx.x;
    int base = blockIdx.x * 1024 + tid * 4;
    int v0 = (base + 0 < N_NODES) ? deg[base + 0] : 0;
    int v1 = (base + 1 < N_NODES) ? deg[base + 1] : 0;
    int v2 = (base + 2 < N_NODES) ? deg[base + 2] : 0;
    int v3 = (base + 3 < N_NODES) ? deg[base + 3] : 0;
    int tsum = v0 + v1 + v2 + v3;
    sd[tid] = tsum;
    __syncthreads();
    for (int d = 1; d < 256; d <<= 1) {
        int t = (tid >= d) ? sd[tid - d] : 0;
        __syncthreads();
        sd[tid] += t;
        __syncthreads();
    }
    int excl = sd[tid] - tsum;
    if (base + 0 < N_NODES) off[base + 0] = excl;
    if (base + 1 < N_NODES) off[base + 1] = excl + v0;
    if (base + 2 < N_NODES) off[base + 2] = excl + v0 + v1;
    if (base + 3 < N_NODES) off[base + 3] = excl + v0 + v1 + v2;
    if (tid == 255) bsum[blockIdx.x] = sd[255];
}

__global__ void k_scan2(const int* __restrict__ bsum, int* __restrict__ bsum2, int nblk) {
    __shared__ int sd[64];
    int tid = threadIdx.x;
    int v = (tid < nblk) ? bsum[tid] : 0;
    sd[tid] = v;
    __syncthreads();
    for (int d = 1; d < 64; d <<= 1) {
        int t = (tid >= d) ? sd[tid - d] : 0;
        __syncthreads();
        sd[tid] += t;
        __syncthreads();
    }
    bsum2[tid] = sd[tid] - v;
}

// also computes dinv (fused)
__global__ void k_scan3(int* __restrict__ off, int* __restrict__ cur,
                        const int* __restrict__ bsum2, const int* __restrict__ deg,
                        float* __restrict__ dinv) {
    int base = blockIdx.x * 1024 + threadIdx.x * 4;
    int add = bsum2[blockIdx.x];
    #pragma unroll
    for (int j = 0; j < 4; ++j) {
        int i = base + j;
        if (i < N_NODES) {
            int v = off[i] + add;
            off[i] = v;
            cur[i] = v;
            dinv[i] = rsqrtf((float)(deg[i] + 1));
        }
    }
}

// fill CSR: srcs + per-slot dinv[src] (kills the per-edge dinv gather in k_agg)
__global__ void k_fill(const int* __restrict__ src, const int* __restrict__ dst,
                       int* __restrict__ cur, int* __restrict__ srcs,
                       float* __restrict__ dsv, const float* __restrict__ dinv) {
    int e = blockIdx.x * 256 + threadIdx.x;
    if (e < N_EDGES) {
        int s = src[e];
        int p = atomicAdd(&cur[dst[e]], 1);
        srcs[p] = s;
        dsv[p] = dinv[s];
    }
}

// ---------------- dense GEMM v2: out[N,128] = A[N,128] @ W[128,128] ----------------
// block: 128 rows x 128 cols, 256 threads, thread tile 4 rows x 16 cols.
// xs stored transposed [k][row] -> a-reads are conflict-free b32 broadcasts;
// w-reads are wave-uniform b128 broadcasts. 8 LDS instr / 64 FMA per k-step.
__global__ __launch_bounds__(256) void k_gemm(const float* __restrict__ A,
                                              const float* __restrict__ W,
                                              float* __restrict__ out) {
    __shared__ float xs[32][132];   // [k][row], pad 132 -> bank (4k+row)%32
    __shared__ float ws[32][128];   // [k][col]
    int tid = threadIdx.x;
    int cg = tid & 7;    // col group: cols cg*4 + j*32
    int rg = tid >> 3;   // row group: rows rg*4 + rr
    int row0 = blockIdx.x * 128;
    float acc[4][16];
    #pragma unroll
    for (int i = 0; i < 4; ++i)
        #pragma unroll
        for (int j = 0; j < 16; ++j) acc[i][j] = 0.f;

    for (int kc = 0; kc < CH; kc += 32) {
        #pragma unroll
        for (int it = 0; it < 4; ++it) {   // x: 128 rows x 32 k, transposed store
            int idx = it * 256 + tid;
            int r = idx >> 3;
            int k4 = (idx & 7) << 2;
            float4 v = make_float4(0.f, 0.f, 0.f, 0.f);
            int gr = row0 + r;
            if (gr < N_NODES) v = *(const float4*)&A[gr * CH + kc + k4];
            xs[k4 + 0][r] = v.x;
            xs[k4 + 1][r] = v.y;
            xs[k4 + 2][r] = v.z;
            xs[k4 + 3][r] = v.w;
        }
        #pragma unroll
        for (int it = 0; it < 4; ++it) {   // W: 32 k x 128 c
            int idx = it * 256 + tid;
            int k = idx >> 5;
            int c4 = (idx & 31) << 2;
            *(float4*)&ws[k][c4] = *(const float4*)&W[(kc + k) * CH + c4];
        }
        __syncthreads();
        #pragma unroll 4
        for (int k = 0; k < 32; ++k) {
            float a0 = xs[k][rg * 4 + 0];
            float a1 = xs[k][rg * 4 + 1];
            float a2 = xs[k][rg * 4 + 2];
            float a3 = xs[k][rg * 4 + 3];
            #pragma unroll
            for (int j = 0; j < 4; ++j) {
                float4 w = *(float4*)&ws[k][cg * 4 + j * 32];
                acc[0][j * 4 + 0] += a0 * w.x; acc[0][j * 4 + 1] += a0 * w.y;
                acc[0][j * 4 + 2] += a0 * w.z; acc[0][j * 4 + 3] += a0 * w.w;
                acc[1][j * 4 + 0] += a1 * w.x; acc[1][j * 4 + 1] += a1 * w.y;
                acc[1][j * 4 + 2] += a1 * w.z; acc[1][j * 4 + 3] += a1 * w.w;
                acc[2][j * 4 + 0] += a2 * w.x; acc[2][j * 4 + 1] += a2 * w.y;
                acc[2][j * 4 + 2] += a2 * w.z; acc[2][j * 4 + 3] += a2 * w.w;
                acc[3][j * 4 + 0] += a3 * w.x; acc[3][j * 4 + 1] += a3 * w.y;
                acc[3][j * 4 + 2] += a3 * w.z; acc[3][j * 4 + 3] += a3 * w.w;
            }
        }
        __syncthreads();
    }
    #pragma unroll
    for (int rr = 0; rr < 4; ++rr) {
        int gr = row0 + rg * 4 + rr;
        if (gr < N_NODES) {
            #pragma unroll
            for (int j = 0; j < 4; ++j) {
                float4 v = make_float4(acc[rr][j * 4 + 0], acc[rr][j * 4 + 1],
                                       acc[rr][j * 4 + 2], acc[rr][j * 4 + 3]);
                *(float4*)&out[gr * CH + cg * 4 + j * 32] = v;
            }
        }
    }
}

// ---------------- aggregation v3: one wave64 per node, lane = float2 channel pair.
// Edge ids/coefs are wave-uniform scalar loads; 8 independent row-gathers in flight,
// padded loop (dummy edges clamp to the node's own last slot -> hot line, coef 0).
__global__ __launch_bounds__(256) void k_agg(const float* __restrict__ h,
                                             const float* __restrict__ dinv,
                                             const int* __restrict__ off,
                                             const int* __restrict__ deg,
                                             const int* __restrict__ srcs,
                                             const float* __restrict__ dsv,
                                             const float* __restrict__ bias,
                                             float* __restrict__ out) {
    int node = __builtin_amdgcn_readfirstlane(blockIdx.x * 4 + (threadIdx.x >> 6));
    int lane = threadIdx.x & 63;
    const float2* hv = (const float2*)h;

    float dn = dinv[node];
    float2 hs = hv[node * 64 + lane];
    float ax = hs.x * dn, ay = hs.y * dn;   // self-loop (coef dn applied at end)

    int start = off[node];
    int cnt = deg[node];
    int last = start + cnt - 1;
    for (int j = 0; j < cnt; j += 8) {
        int i0 = start + j;
        int i1 = min(i0 + 1, last);
        int i2 = min(i0 + 2, last);
        int i3 = min(i0 + 3, last);
        int i4 = min(i0 + 4, last);
        int i5 = min(i0 + 5, last);
        int i6 = min(i0 + 6, last);
        int i7 = min(i0 + 7, last);
        int s0 = srcs[i0], s1 = srcs[i1], s2 = srcs[i2], s3 = srcs[i3];
        int s4 = srcs[i4], s5 = srcs[i5], s6 = srcs[i6], s7 = srcs[i7];
        int rem = cnt - j;
        float d0 = dsv[i0];
        float d1 = (rem > 1) ? dsv[i1] : 0.f;
        float d2 = (rem > 2) ? dsv[i2] : 0.f;
        float d3 = (rem > 3) ? dsv[i3] : 0.f;
        float d4 = (rem > 4) ? dsv[i4] : 0.f;
        float d5 = (rem > 5) ? dsv[i5] : 0.f;
        float d6 = (rem > 6) ? dsv[i6] : 0.f;
        float d7 = (rem > 7) ? dsv[i7] : 0.f;
        float2 v0 = hv[s0 * 64 + lane];
        float2 v1 = hv[s1 * 64 + lane];
        float2 v2 = hv[s2 * 64 + lane];
        float2 v3 = hv[s3 * 64 + lane];
        float2 v4 = hv[s4 * 64 + lane];
        float2 v5 = hv[s5 * 64 + lane];
        float2 v6 = hv[s6 * 64 + lane];
        float2 v7 = hv[s7 * 64 + lane];
        ax += v0.x * d0; ay += v0.y * d0;
        ax += v1.x * d1; ay += v1.y * d1;
        ax += v2.x * d2; ay += v2.y * d2;
        ax += v3.x * d3; ay += v3.y * d3;
        ax += v4.x * d4; ay += v4.y * d4;
        ax += v5.x * d5; ay += v5.y * d5;
        ax += v6.x * d6; ay += v6.y * d6;
        ax += v7.x * d7; ay += v7.y * d7;
    }
    float2 b = ((const float2*)bias)[lane];
    ax = fmaxf(ax * dn + b.x, 0.f);
    ay = fmaxf(ay * dn + b.y, 0.f);
    ((float2*)out)[node * 64 + lane] = make_float2(ax, ay);
}

// ---------------- fused mean-pool + linear (batch is sorted) ----------------
__global__ void k_pool_linear(const float* __restrict__ h, const int* __restrict__ batch,
                              const float* __restrict__ Wl, const float* __restrict__ bl,
                              float* __restrict__ out) {
    __shared__ int sb[2];
    __shared__ float xr[CH];
    int g = blockIdx.x;
    if (threadIdx.x < 2) {
        int target = g + (int)threadIdx.x;
        int lo = 0, hi = N_NODES;
        while (lo < hi) {
            int mid = (lo + hi) >> 1;
            if (batch[mid] < target) lo = mid + 1; else hi = mid;
        }
        sb[threadIdx.x] = lo;
    }
    __syncthreads();
    int lo = sb[0], hi = sb[1];
    int c = threadIdx.x;  // 128 threads
    float acc = 0.f;
    for (int i = lo; i < hi; ++i) acc += h[i * CH + c];
    float cnt = (float)((hi - lo) > 0 ? (hi - lo) : 1);
    xr[c] = acc / cnt;
    __syncthreads();
    if (c < OUT_CH) {
        float o = bl[c];
        #pragma unroll 8
        for (int k = 0; k < CH; ++k) o += xr[k] * Wl[k * OUT_CH + c];
        out[g * OUT_CH + c] = o;
    }
}

extern "C" void kernel_launch(void* const* d_in, const int* in_sizes, int n_in,
                              void* d_out, int out_size, void* d_ws, size_t ws_size,
                              hipStream_t stream) {
    const float* x    = (const float*)d_in[0];
    const float* W1   = (const float*)d_in[1];
    const float* b1   = (const float*)d_in[2];
    const float* W2   = (const float*)d_in[3];
    const float* b2   = (const float*)d_in[4];
    const float* Wlin = (const float*)d_in[5];
    const float* blin = (const float*)d_in[6];
    const int* ei     = (const int*)d_in[7];
    const int* batch  = (const int*)d_in[8];
    const int* esrc = ei;
    const int* edst = ei + N_EDGES;
    float* out = (float*)d_out;

    char* w = (char*)d_ws;
    size_t o = 0;
    float* h1     = (float*)(w + o); o += (size_t)N_NODES * CH * 4;
    float* h2     = (float*)(w + o); o += (size_t)N_NODES * CH * 4;
    float* dinv   = (float*)(w + o); o += 200704;
    int* deg      = (int*)(w + o);   o += 200704;
    int* off      = (int*)(w + o);   o += 200704;
    int* cur      = (int*)(w + o);   o += 200704;
    int* srcs     = (int*)(w + o);   o += (size_t)N_EDGES * 4;
    float* dsv    = (float*)(w + o); o += (size_t)N_EDGES * 4;
    int* bsum     = (int*)(w + o);   o += 256;
    int* bsum2    = (int*)(w + o);   o += 256;
    (void)ws_size; (void)in_sizes; (void)n_in; (void)out_size;

    hipMemsetAsync(deg, 0, N_NODES * sizeof(int), stream);

    dim3 b256(256);
    dim3 gE((N_EDGES + 255) / 256);
    k_count<<<gE, b256, 0, stream>>>(edst, deg);
    k_scan1<<<dim3(49), b256, 0, stream>>>(deg, off, bsum);
    k_scan2<<<dim3(1), dim3(64), 0, stream>>>(bsum, bsum2, 49);
    k_scan3<<<dim3(49), b256, 0, stream>>>(off, cur, bsum2, deg, dinv);
    k_fill<<<gE, b256, 0, stream>>>(esrc, edst, cur, srcs, dsv, dinv);

    dim3 gG((N_NODES + 127) / 128);   // 391
    dim3 gA(N_NODES / 4);             // 12500, one wave64 per node
    k_gemm<<<gG, b256, 0, stream>>>(x, W1, h1);
    k_agg<<<gA, b256, 0, stream>>>(h1, dinv, off, deg, srcs, dsv, b1, h2);
    k_gemm<<<gG, b256, 0, stream>>>(h2, W2, h1);
    k_agg<<<gA, b256, 0, stream>>>(h1, dinv, off, deg, srcs, dsv, b2, h2);
    k_pool_linear<<<dim3(NUM_GRAPHS), dim3(128), 0, stream>>>(h2, batch, Wlin, blin, out);
}